// Round 1
// baseline (306.769 us; speedup 1.0000x reference)
//
#include <hip/hip_runtime.h>
#include <math.h>

// SuperLoss elementwise:
//   il    = BCE_with_logits(pr, gt) = max(pr,0) - pr*gt + log1p(exp(-|pr|))   (always >= 0)
//   y     = 0.5 * max(BETA0, il)  -> since il >= 0, y = 0.5*il >= 0 (clamp never fires)
//   w     = LambertW(y)  (principal branch, Halley iterations; y >= 0 so well-conditioned)
//   sigma = exp(-w)
//   out   = sigma * il + w*w          (since log(sigma)^2 = w^2, TAU=0, LAM=1)
//
// Memory-bound: 402 MB traffic -> ~64 us floor at 6.3 TB/s.

#define SL_BETA0 (-2.0f / (2.718281828459045f + 0.08f))

__device__ __forceinline__ float superloss_elem(float pr, float gt) {
    // Numerically-stable BCE with logits
    float t  = __expf(-fabsf(pr));
    float il = fmaxf(pr, 0.0f) - pr * gt + __logf(1.0f + t);

    float y = 0.5f * fmaxf(SL_BETA0, il);   // y >= 0 in practice
    // Lambert W via Halley, init w = log1p(y). Cubic convergence; 4 iters
    // reach fp32 fixed point for y in [0, ~10].
    float w = __logf(1.0f + y);
#pragma unroll
    for (int it = 0; it < 4; ++it) {
        float e   = __expf(w);
        float f   = __fmaf_rn(w, e, -y);                       // w*e - y
        float wp1 = w + 1.0f;
        // denominator: e*(w+1) - (w+2)*f / (2w+2)
        float den = __fmaf_rn(e, wp1,
                              -(w + 2.0f) * f * __builtin_amdgcn_rcpf(2.0f * wp1));
        w = __fmaf_rn(-f, __builtin_amdgcn_rcpf(den), w);
    }
    float sigma = __expf(-w);
    return __fmaf_rn(sigma, il, w * w);
}

__global__ __launch_bounds__(256) void superloss_vec4(const float4* __restrict__ pr,
                                                      const float4* __restrict__ gt,
                                                      float4* __restrict__ out,
                                                      int n4) {
    int i = blockIdx.x * blockDim.x + threadIdx.x;
    if (i < n4) {
        float4 p = pr[i];
        float4 g = gt[i];
        float4 o;
        o.x = superloss_elem(p.x, g.x);
        o.y = superloss_elem(p.y, g.y);
        o.z = superloss_elem(p.z, g.z);
        o.w = superloss_elem(p.w, g.w);
        out[i] = o;
    }
}

__global__ __launch_bounds__(256) void superloss_scalar(const float* __restrict__ pr,
                                                        const float* __restrict__ gt,
                                                        float* __restrict__ out,
                                                        int base, int n) {
    int i = base + blockIdx.x * blockDim.x + threadIdx.x;
    if (i < n) {
        out[i] = superloss_elem(pr[i], gt[i]);
    }
}

extern "C" void kernel_launch(void* const* d_in, const int* in_sizes, int n_in,
                              void* d_out, int out_size, void* d_ws, size_t ws_size,
                              hipStream_t stream) {
    const float* pr = (const float*)d_in[0];
    const float* gt = (const float*)d_in[1];
    float* out = (float*)d_out;
    int n = in_sizes[0];

    int n4 = n / 4;
    if (n4 > 0) {
        int blocks = (n4 + 255) / 256;
        superloss_vec4<<<blocks, 256, 0, stream>>>((const float4*)pr, (const float4*)gt,
                                                   (float4*)out, n4);
    }
    int rem = n - n4 * 4;
    if (rem > 0) {
        superloss_scalar<<<1, 256, 0, stream>>>(pr, gt, out, n4 * 4, n);
    }
}

// Round 2
// 299.412 us; speedup vs baseline: 1.0246x; 1.0246x over previous
//
#include <hip/hip_runtime.h>
#include <math.h>

// SuperLoss elementwise (LAM=1, TAU=0):
//   il  = BCE_with_logits(pr, gt) = max(pr,0) - pr*gt + log1p(exp(-|pr|))  (>= 0)
//   y   = il/2   (the BETA0 clamp never fires since il >= 0 > BETA0)
//   w   = LambertW(y), principal branch
//   out = sigma*il + log(sigma)^2  with sigma = exp(-w)
//
// KEY IDENTITY: w*e^w = y  =>  e^{-w} = w/y = 2w/il  =>  sigma*il = 2w.
//   out = 2w + w^2 = w*(w+2).   No sigma exp needed.
//
// Lambert W: w0 = log1p(y), then 2 Halley iterations (cubic; |err| ~4e-7 for
// y in [0,3], data range). Halley rearranged to ONE rcp per iter:
//   f = w*e^w - y
//   w -= 2*f*(w+1) / (2*e^w*(w+1)^2 - (w+2)*f)
//
// Trans-op budget/elem: exp+log (BCE) + log (init) + 2*(exp+rcp) = 7
// (was 16). VALU-bound -> ~25-30 us compute, memory mix bound thereafter.

__device__ __forceinline__ float superloss_elem(float pr, float gt) {
    // Numerically-stable BCE with logits
    float t  = __expf(-fabsf(pr));
    float il = fmaxf(pr, 0.0f) - pr * gt + __logf(1.0f + t);

    float y = 0.5f * il;            // y >= 0
    float w = __logf(1.0f + y);     // init: log1p(y)

#pragma unroll
    for (int it = 0; it < 2; ++it) {
        float e   = __expf(w);
        float f   = __fmaf_rn(w, e, -y);            // w*e^w - y
        float wp1 = w + 1.0f;
        float num = 2.0f * f * wp1;
        // den = 2*e*(w+1)^2 - (w+2)*f
        float den = __fmaf_rn(2.0f * e, wp1 * wp1, -(w + 2.0f) * f);
        w = __fmaf_rn(-num, __builtin_amdgcn_rcpf(den), w);
    }
    // out = sigma*il + w^2 = 2w + w^2 = w*(w+2)
    return w * (w + 2.0f);
}

__global__ __launch_bounds__(256) void superloss_vec4(const float4* __restrict__ pr,
                                                      const float4* __restrict__ gt,
                                                      float4* __restrict__ out,
                                                      int n4) {
    int i = blockIdx.x * blockDim.x + threadIdx.x;
    if (i < n4) {
        float4 p = pr[i];
        float4 g = gt[i];
        float4 o;
        o.x = superloss_elem(p.x, g.x);
        o.y = superloss_elem(p.y, g.y);
        o.z = superloss_elem(p.z, g.z);
        o.w = superloss_elem(p.w, g.w);
        out[i] = o;
    }
}

__global__ __launch_bounds__(256) void superloss_scalar(const float* __restrict__ pr,
                                                        const float* __restrict__ gt,
                                                        float* __restrict__ out,
                                                        int base, int n) {
    int i = base + blockIdx.x * blockDim.x + threadIdx.x;
    if (i < n) {
        out[i] = superloss_elem(pr[i], gt[i]);
    }
}

extern "C" void kernel_launch(void* const* d_in, const int* in_sizes, int n_in,
                              void* d_out, int out_size, void* d_ws, size_t ws_size,
                              hipStream_t stream) {
    const float* pr = (const float*)d_in[0];
    const float* gt = (const float*)d_in[1];
    float* out = (float*)d_out;
    int n = in_sizes[0];

    int n4 = n / 4;
    if (n4 > 0) {
        int blocks = (n4 + 255) / 256;
        superloss_vec4<<<blocks, 256, 0, stream>>>((const float4*)pr, (const float4*)gt,
                                                   (float4*)out, n4);
    }
    int rem = n - n4 * 4;
    if (rem > 0) {
        superloss_scalar<<<1, 256, 0, stream>>>(pr, gt, out, n4 * 4, n);
    }
}